// Round 11
// baseline (335.220 us; speedup 1.0000x reference)
//
#include <hip/hip_runtime.h>

// B=4, C=256, HS=WS=64 -> N=4096 pixels/batch, 16384 total.
// NK=NV=32, NH=8, QKV = 1088, NH*QKV = 8704.
#define NPIX_TOTAL 16384
#define CDIM 256
#define NHEADS 8
#define QKVD 1088
#define NQKV 8704

typedef unsigned short u16;
typedef __attribute__((ext_vector_type(8))) __bf16 bf16x8;
typedef __attribute__((ext_vector_type(4))) float f32x4;
typedef __attribute__((ext_vector_type(16))) float f32x16;
typedef __attribute__((ext_vector_type(2))) unsigned u32x2;

__device__ static inline u16 f2bf(float f) {
  union { float f; unsigned u; } x; x.f = f;
  unsigned r = x.u + 0x7fffu + ((x.u >> 16) & 1u);
  return (u16)(r >> 16);
}
__device__ static inline float bf2f(u16 b) {
  union { unsigned u; float f; } x; x.u = ((unsigned)b) << 16;
  return x.f;
}

__device__ static inline void gload_lds16(const void* g, void* l) {
  __builtin_amdgcn_global_load_lds((const __attribute__((address_space(1))) void*)g,
                                   (__attribute__((address_space(3))) void*)l,
                                   16, 0, 0);
}

// ---------------------------------------------------------------------------
__global__ __launch_bounds__(256) void transpose_cast(const float* __restrict__ x,
                                                      u16* __restrict__ xt) {
  __shared__ float t[64][65];
  const int b = blockIdx.z;
  const float* xb = x + (size_t)b * CDIM * 4096;
  u16* ob = xt + (size_t)b * 4096 * CDIM;
  const int n0 = blockIdx.x * 64;
  const int c0 = blockIdx.y * 64;
  const int tx = threadIdx.x & 63;
  const int ty = threadIdx.x >> 6;
#pragma unroll
  for (int i = 0; i < 16; ++i)
    t[ty + i * 4][tx] = xb[(size_t)(c0 + ty + i * 4) * 4096 + n0 + tx];
  __syncthreads();
#pragma unroll
  for (int i = 0; i < 16; ++i)
    ob[(size_t)(n0 + ty + i * 4) * CDIM + c0 + tx] = f2bf(t[tx][ty + i * 4]);
}

__global__ __launch_bounds__(256) void cast_bf(const float* __restrict__ in,
                                               u16* __restrict__ out, int n) {
  const int i = (blockIdx.x * 256 + threadIdx.x) * 4;
  if (i >= n) return;
  const f32x4 v = *(const f32x4*)(in + i);
  *(unsigned*)(out + i) = (unsigned)f2bf(v.x) | ((unsigned)f2bf(v.y) << 16);
  *(unsigned*)(out + i + 2) = (unsigned)f2bf(v.z) | ((unsigned)f2bf(v.w) << 16);
}

// ---------------------------------------------------------------------------
// Fused per-head qkv-GEMM + attention, 32x32x16 MFMA main loop, barrier-free.
// Block = 128 pixels x 1 head, 512 thr = 8 waves (wr 2 pixel-halves x wn 4).
// Register budget fits 128 (VGPR+AGPR unified): acc 2xf32x16 + qkr 2xf32x16
// = 64 persistent + W-dbuf 8 + addressing ~30 -> 4 waves/SIMD under (512,4)
// WITHOUT spill (R10's 16x16 diet needed ~140 -> 24-slot spill).
// LDS = A 64KB + q 8KB + v 8KB = 80KB -> exactly 2 blocks/CU.
// Main loop: wave (wr,wn), pass p=0..7 handles k-group g = p*4+wn (32 W-rows
// = all 32 v of k=g) x 64 pix (2 ptiles of 32). Swapped-operand MFMA:
// D col(lane&31)=pixel, row=(reg&3)+8*(reg>>2)+4*(lane>>5)=v (m101-verified).
// After 16 ksteps (K=256): qkr += q[pix][g] * acc (g wave-uniform, pix
// lane-local, 16 v-partials/lane). Epilogue: chunk-swizzled f32 partials
// ([wn][128][32] overlay on A_lds, chunk c=v>>2 at c^(pix&7)) -> R4-proven
// cross-wave sum + softmax; v from v_lds (bf16).
__global__ __launch_bounds__(512, 4) void fused_qkv_attn(const u16* __restrict__ Xbf,
                                                         const u16* __restrict__ Wbf,
                                                         u16* __restrict__ Abf) {
  __shared__ u16 A_lds[128 * 256];  // 64 KB; f32 partials overlay in epilogue
  __shared__ u16 q_lds[128 * 32];   // 8 KB, q[pix][k] bf16, chunk-swizzled
  __shared__ u16 v_lds[128 * 32];   // 8 KB, v[pix][vcol] bf16, plain

  const int tid = threadIdx.x;
  const int lane = tid & 63;
  const int l15 = lane & 15;
  const int l31 = lane & 31;
  const int hi4 = lane >> 4;   // 0..3 (16x16 frags, epilogue)
  const int h2 = lane >> 5;    // 0..1 (32x32 frags)
  const int wid = tid >> 6;    // 0..7
  const int wr = wid >> 2;     // pixel half
  const int wn = wid & 3;      // k-group lane / N quarter
  const int wm = wr * 64;

  const int head = blockIdx.x & 7;   // head pinned per XCD (heuristic)
  const int pixtile = blockIdx.x >> 3;
  const u16* Ag = Xbf + (size_t)pixtile * 128 * CDIM;
  const u16* Wh = Wbf + (size_t)head * QKVD * CDIM;

  // ---- A staging: global source pre-swizzled, LDS linear ----
#pragma unroll
  for (int i = 0; i < 8; ++i) {
    const int seg = wid * 8 + i;
    const int L = seg * 64 + lane;         // 16B chunk 0..4095
    const int row = L >> 5;                // 0..127
    const int c = L & 31;
    const int cs = (c & 24) | ((c & 7) ^ (row & 7));
    gload_lds16(Ag + (size_t)row * CDIM + cs * 8, (char*)A_lds + (size_t)seg * 1024);
  }
  __syncthreads();  // A_lds ready (barrier drains gload_lds)

  auto afrag = [&](int mi, int kb, int kk2) -> bf16x8 {
    const int row = wm + mi * 16 + l15;
    const int ch = kb * 8 + ((kk2 * 4 + hi4) ^ (row & 7));
    return *(const bf16x8*)(A_lds + row * 256 + ch * 8);
  };

  // ---- qv sub-GEMM (16x16): wave (wr,wn): 64 pix x 16 qv-cols ----
  {
    f32x4 accq[4] = {};
    const int brow = wn * 16 + l15;
    const u16* qvbase = Wh + (size_t)(brow < 32 ? brow : brow + 1024) * CDIM + hi4 * 8;
#pragma unroll
    for (int kb = 0; kb < 4; ++kb)
#pragma unroll
      for (int kk2 = 0; kk2 < 2; ++kk2) {
        const bf16x8 bq = *(const bf16x8*)(qvbase + kb * 64 + kk2 * 32);
#pragma unroll
        for (int mi = 0; mi < 4; ++mi)
          accq[mi] = __builtin_amdgcn_mfma_f32_16x16x32_bf16(bq, afrag(mi, kb, kk2),
                                                             accq[mi], 0, 0, 0);
      }
    if (wn < 2) {  // stash q[pix][k] bf16, chunk-swizzled (k = wn*16+hi4*4+j)
#pragma unroll
      for (int mi = 0; mi < 4; ++mi) {
        const int pix = wm + mi * 16 + l15;
        u32x2 p;
        p.x = (unsigned)f2bf(accq[mi].x) | ((unsigned)f2bf(accq[mi].y) << 16);
        p.y = (unsigned)f2bf(accq[mi].z) | ((unsigned)f2bf(accq[mi].w) << 16);
        *(u32x2*)(q_lds + pix * 32 + ((wn * 4 + hi4) ^ (pix & 7)) * 4) = p;
      }
    } else {      // stash v[pix][vcol] bf16, plain (vcol = (wn-2)*16+hi4*4+j)
#pragma unroll
      for (int mi = 0; mi < 4; ++mi) {
        const int pix = wm + mi * 16 + l15;
        u32x2 p;
        p.x = (unsigned)f2bf(accq[mi].x) | ((unsigned)f2bf(accq[mi].y) << 16);
        p.y = (unsigned)f2bf(accq[mi].z) | ((unsigned)f2bf(accq[mi].w) << 16);
        *(u32x2*)(v_lds + pix * 32 + (wn - 2) * 16 + hi4 * 4) = p;
      }
    }
  }
  __syncthreads();  // q,v visible; accq dead -> registers free

  // ---- main loop: 8 passes x 16 ksteps, 32x32x16, W global->reg dbuf ----
  const int pix0 = wm + l31;
  const int pix1 = pix0 + 32;
  f32x16 acc0 = {}, acc1 = {}, qkr0 = {}, qkr1 = {};

  auto wload = [&](int u) -> bf16x8 {   // u = pass*16 + kstep
    const int g = (u >> 4) * 4 + wn;
    const int ks = u & 15;
    return *(const bf16x8*)(Wh + (size_t)(32 + g * 32 + l31) * CDIM + ks * 16 + h2 * 8);
  };
  auto xfrag = [&](int row, int c) -> bf16x8 {
    const int sc = (c & 24) | ((c & 7) ^ (row & 7));
    return *(const bf16x8*)(A_lds + row * 256 + sc * 8);
  };

  bf16x8 wA = wload(0), wB = wload(1);
#pragma unroll 1
  for (int p = 0; p < 8; ++p) {
#pragma unroll
    for (int k2 = 0; k2 < 16; k2 += 2) {
      const int u = p * 16 + k2;
      __builtin_amdgcn_s_setprio(1);
      acc0 = __builtin_amdgcn_mfma_f32_32x32x16_bf16(wA, xfrag(pix0, k2 * 2 + h2), acc0, 0, 0, 0);
      acc1 = __builtin_amdgcn_mfma_f32_32x32x16_bf16(wA, xfrag(pix1, k2 * 2 + h2), acc1, 0, 0, 0);
      __builtin_amdgcn_s_setprio(0);
      if (u + 2 < 128) wA = wload(u + 2);
      __builtin_amdgcn_s_setprio(1);
      acc0 = __builtin_amdgcn_mfma_f32_32x32x16_bf16(wB, xfrag(pix0, k2 * 2 + 2 + h2), acc0, 0, 0, 0);
      acc1 = __builtin_amdgcn_mfma_f32_32x32x16_bf16(wB, xfrag(pix1, k2 * 2 + 2 + h2), acc1, 0, 0, 0);
      __builtin_amdgcn_s_setprio(0);
      if (u + 3 < 128) wB = wload(u + 3);
    }
    // contraction for k-group g: qkr += q[pix][g] * acc (16 v-partials/lane)
    const int g = p * 4 + wn;
    const float q0 = bf2f(q_lds[pix0 * 32 + (((g >> 2) ^ (pix0 & 7)) * 4) + (g & 3)]);
    const float q1 = bf2f(q_lds[pix1 * 32 + (((g >> 2) ^ (pix1 & 7)) * 4) + (g & 3)]);
    qkr0 += acc0 * q0;
    qkr1 += acc1 * q1;
    const f32x16 z = {};
    acc0 = z;
    acc1 = z;
  }

  // ---- epilogue: partials -> cross-wave sum -> softmax -> a = p*v ----
  __syncthreads();                 // all waves done with A_lds / q_lds
  float* part = (float*)A_lds;     // [wn 4][pix 128][v 32] f32 = 64 KB
#pragma unroll
  for (int gi = 0; gi < 4; ++gi) {
    // reg r=gi*4+j -> v = 8*gi + 4*h2 + j -> chunk c = v>>2 = 2*gi + h2
    const f32x4 a0 = {qkr0[gi * 4 + 0], qkr0[gi * 4 + 1], qkr0[gi * 4 + 2], qkr0[gi * 4 + 3]};
    const f32x4 a1 = {qkr1[gi * 4 + 0], qkr1[gi * 4 + 1], qkr1[gi * 4 + 2], qkr1[gi * 4 + 3]};
    const int c = 2 * gi + h2;
    *(f32x4*)(part + wn * 4096 + pix0 * 32 + (c ^ (pix0 & 7)) * 4) = a0;
    *(f32x4*)(part + wn * 4096 + pix1 * 32 + (c ^ (pix1 & 7)) * 4) = a1;
  }
  __syncthreads();

  const float scale = 0.17677669529663687f;  // 1/sqrt(32)
  const int pix = wid * 16 + l15;            // 8 waves x 16 = 128 pixels
  const int ch0 = hi4 ^ (pix & 7);           // logical chunk hi4   -> v 4*hi4..+3
  const int ch1 = (4 + hi4) ^ (pix & 7);     // logical chunk hi4+4 -> v 16+4*hi4..+3
  f32x4 s0 = {}, s1 = {};
#pragma unroll
  for (int w = 0; w < 4; ++w) {
    s0 += *(const f32x4*)(part + w * 4096 + pix * 32 + ch0 * 4);
    s1 += *(const f32x4*)(part + w * 4096 + pix * 32 + ch1 * 4);
  }
  s0 *= scale;
  s1 *= scale;
  float m = fmaxf(fmaxf(fmaxf(s0.x, s0.y), fmaxf(s0.z, s0.w)),
                  fmaxf(fmaxf(s1.x, s1.y), fmaxf(s1.z, s1.w)));
  m = fmaxf(m, __shfl_xor(m, 16));
  m = fmaxf(m, __shfl_xor(m, 32));
  f32x4 e0, e1;
  e0.x = __expf(s0.x - m); e0.y = __expf(s0.y - m);
  e0.z = __expf(s0.z - m); e0.w = __expf(s0.w - m);
  e1.x = __expf(s1.x - m); e1.y = __expf(s1.y - m);
  e1.z = __expf(s1.z - m); e1.w = __expf(s1.w - m);
  float su = e0.x + e0.y + e0.z + e0.w + e1.x + e1.y + e1.z + e1.w;
  su += __shfl_xor(su, 16);
  su += __shfl_xor(su, 32);
  const float inv = 1.0f / su;
  const u16* vrow = v_lds + pix * 32;
  const f32x4 v0 = {bf2f(vrow[hi4 * 4 + 0]), bf2f(vrow[hi4 * 4 + 1]),
                    bf2f(vrow[hi4 * 4 + 2]), bf2f(vrow[hi4 * 4 + 3])};
  const f32x4 v1 = {bf2f(vrow[16 + hi4 * 4 + 0]), bf2f(vrow[16 + hi4 * 4 + 1]),
                    bf2f(vrow[16 + hi4 * 4 + 2]), bf2f(vrow[16 + hi4 * 4 + 3])};
  const f32x4 o0 = e0 * v0 * inv;
  const f32x4 o1 = e1 * v1 * inv;
  u16* dst = Abf + (size_t)(pixtile * 128 + pix) * 256 + head * 32;
  u32x2 p0, p1;
  p0.x = (unsigned)f2bf(o0.x) | ((unsigned)f2bf(o0.y) << 16);
  p0.y = (unsigned)f2bf(o0.z) | ((unsigned)f2bf(o0.w) << 16);
  p1.x = (unsigned)f2bf(o1.x) | ((unsigned)f2bf(o1.y) << 16);
  p1.y = (unsigned)f2bf(o1.z) | ((unsigned)f2bf(o1.w) << 16);
  *(u32x2*)(dst + hi4 * 4) = p0;
  *(u32x2*)(dst + 16 + hi4 * 4) = p1;
}

// ---------------------------------------------------------------------------
// gemm2: out = a @ Wc^T + bc -> (B, C, 4096). 128x128, 2-phase dbuf, swizzled.
__global__ __launch_bounds__(256, 2) void gemm_out(const u16* __restrict__ A,
                                                   const u16* __restrict__ B,
                                                   float* __restrict__ Cout,
                                                   const float* __restrict__ bias) {
  __shared__ u16 As[2][128 * 64];
  __shared__ u16 Bs[2][128 * 64];
  const int tid = threadIdx.x;
  const int lane = tid & 63;
  const int wv = tid >> 6;
  const size_t m0 = (size_t)blockIdx.y * 128;
  const size_t n0 = (size_t)blockIdx.x * 128;
  const int wm = (wv >> 1) * 64;
  const int wn = (wv & 1) * 64;
  const int frow = lane & 15;
  const int fh = lane >> 4;
  const int fsw = frow & 7;

  f32x4 acc[4][4] = {};

  auto stage = [&](int buf, int kt) {
#pragma unroll
    for (int i = 0; i < 4; ++i) {
      const int L = (i * 4 + wv) * 64 + lane;
      const int r = L >> 3;
      const int cs = (L & 7) ^ (r & 7);
      const size_t goff = (size_t)r * CDIM + kt * 64 + cs * 8;
      gload_lds16(A + m0 * CDIM + goff, (char*)As[buf] + (size_t)(i * 4 + wv) * 1024);
      gload_lds16(B + n0 * CDIM + goff, (char*)Bs[buf] + (size_t)(i * 4 + wv) * 1024);
    }
  };

  stage(0, 0);
#pragma unroll
  for (int kt = 0; kt < 4; ++kt) {
    __syncthreads();
    if (kt < 3) stage((kt + 1) & 1, kt + 1);
    const u16* as = As[kt & 1];
    const u16* bs = Bs[kt & 1];
#pragma unroll
    for (int kk2 = 0; kk2 < 2; ++kk2) {
      const int kc = (kk2 * 4 + fh) ^ fsw;
      bf16x8 af[4], bfr[4];
#pragma unroll
      for (int mi = 0; mi < 4; ++mi)
        af[mi] = *(const bf16x8*)(as + (wm + mi * 16 + frow) * 64 + kc * 8);
#pragma unroll
      for (int ni = 0; ni < 4; ++ni)
        bfr[ni] = *(const bf16x8*)(bs + (wn + ni * 16 + frow) * 64 + kc * 8);
#pragma unroll
      for (int mi = 0; mi < 4; ++mi)
#pragma unroll
        for (int ni = 0; ni < 4; ++ni)
          acc[mi][ni] =
              __builtin_amdgcn_mfma_f32_16x16x32_bf16(af[mi], bfr[ni], acc[mi][ni], 0, 0, 0);
    }
  }

#pragma unroll
  for (int mi = 0; mi < 4; ++mi)
#pragma unroll
    for (int ni = 0; ni < 4; ++ni) {
      const size_t gm = m0 + wm + mi * 16 + fh * 4;
      const size_t gn = n0 + wn + ni * 16 + frow;
      f32x4 v = acc[mi][ni];
      v += bias[gn];
      const size_t b = gm >> 12;
      const size_t pix = gm & 4095;
      *(f32x4*)(Cout + ((b << 8) + gn) * 4096 + pix) = v;
    }
}

// ---------------------------------------------------------------------------
extern "C" void kernel_launch(void* const* d_in, const int* in_sizes, int n_in,
                              void* d_out, int out_size, void* d_ws, size_t ws_size,
                              hipStream_t stream) {
  (void)in_sizes; (void)n_in; (void)out_size; (void)ws_size;
  const float* x = (const float*)d_in[0];     // (4, 256, 64, 64)
  const float* Wqkv = (const float*)d_in[1];  // (8, 1088, 256)
  const float* Wc = (const float*)d_in[2];    // (256, 256)
  const float* bc = (const float*)d_in[3];    // (256,)
  float* out = (float*)d_out;                 // (4, 256, 64, 64)
  char* ws = (char*)d_ws;

  const size_t XBF_OFF = 0;               // 16384*256*2 = 8388608
  const size_t WBF_OFF = 8388608;         // 8704*256*2  = 4456448
  const size_t WCBF_OFF = 12845056;       // 256*256*2   = 131072
  const size_t ABF_OFF = 12976128;        // 16384*256*2 = 8388608
  u16* Xbf = (u16*)(ws + XBF_OFF);
  u16* Wbf = (u16*)(ws + WBF_OFF);
  u16* Wcbf = (u16*)(ws + WCBF_OFF);
  u16* Abf = (u16*)(ws + ABF_OFF);

  // stage 0: convert inputs to bf16
  transpose_cast<<<dim3(64, 4, 4), 256, 0, stream>>>(x, Xbf);
  cast_bf<<<(NQKV * CDIM) / 1024, 256, 0, stream>>>(Wqkv, Wbf, NQKV * CDIM);
  cast_bf<<<(CDIM * 256) / 1024, 256, 0, stream>>>(Wc, Wcbf, CDIM * 256);

  // stage 1: fused qkv-GEMM + attention (128 pix x 1 head, 32x32x16 MFMA,
  // 80 KB LDS + ~110 regs -> 2 blocks/CU = 4 waves/SIMD, barrier-free)
  fused_qkv_attn<<<dim3((NPIX_TOTAL / 128) * NHEADS), 512, 0, stream>>>(Xbf, Wbf, Abf);

  // stage 2: out = a @ Wc^T + bc -> (B, C, 4096)
  gemm_out<<<dim3(256 / 128, NPIX_TOTAL / 128), 256, 0, stream>>>(Abf, Wcbf, out, bc);
}

// Round 12
// 121.516 us; speedup vs baseline: 2.7586x; 2.7586x over previous
//
#include <hip/hip_runtime.h>

// B=4, C=256, HS=WS=64 -> N=4096 pixels/batch, 16384 total.
// NK=NV=32, NH=8, QKV = 1088, NH*QKV = 8704.
#define NPIX_TOTAL 16384
#define CDIM 256
#define NHEADS 8
#define QKVD 1088
#define NQKV 8704

typedef unsigned short u16;
typedef __attribute__((ext_vector_type(8))) __bf16 bf16x8;
typedef __attribute__((ext_vector_type(4))) float f32x4;
typedef __attribute__((ext_vector_type(2))) unsigned u32x2;

__device__ static inline u16 f2bf(float f) {
  union { float f; unsigned u; } x; x.f = f;
  unsigned r = x.u + 0x7fffu + ((x.u >> 16) & 1u);
  return (u16)(r >> 16);
}

__device__ static inline void gload_lds16(const void* g, void* l) {
  __builtin_amdgcn_global_load_lds((const __attribute__((address_space(1))) void*)g,
                                   (__attribute__((address_space(3))) void*)l,
                                   16, 0, 0);
}

#define WAITVM(N) asm volatile("s_waitcnt vmcnt(" #N ")" ::: "memory")

// ---------------------------------------------------------------------------
__global__ __launch_bounds__(256) void transpose_cast(const float* __restrict__ x,
                                                      u16* __restrict__ xt) {
  __shared__ float t[64][65];
  const int b = blockIdx.z;
  const float* xb = x + (size_t)b * CDIM * 4096;
  u16* ob = xt + (size_t)b * 4096 * CDIM;
  const int n0 = blockIdx.x * 64;
  const int c0 = blockIdx.y * 64;
  const int tx = threadIdx.x & 63;
  const int ty = threadIdx.x >> 6;
#pragma unroll
  for (int i = 0; i < 16; ++i)
    t[ty + i * 4][tx] = xb[(size_t)(c0 + ty + i * 4) * 4096 + n0 + tx];
  __syncthreads();
#pragma unroll
  for (int i = 0; i < 16; ++i)
    ob[(size_t)(n0 + ty + i * 4) * CDIM + c0 + tx] = f2bf(t[tx][ty + i * 4]);
}

__global__ __launch_bounds__(256) void cast_bf(const float* __restrict__ in,
                                               u16* __restrict__ out, int n) {
  const int i = (blockIdx.x * 256 + threadIdx.x) * 4;
  if (i >= n) return;
  const f32x4 v = *(const f32x4*)(in + i);
  *(unsigned*)(out + i) = (unsigned)f2bf(v.x) | ((unsigned)f2bf(v.y) << 16);
  *(unsigned*)(out + i + 2) = (unsigned)f2bf(v.z) | ((unsigned)f2bf(v.w) << 16);
}

// ---------------------------------------------------------------------------
// Fused per-head qkv-GEMM + per-pixel attention.
// Champion (R3, 105us) structure with the main-loop s_barriers REMOVED:
// each wave (wr,wn) reads only B rows wn*64..+64, so B slabs are WAVE-PRIVATE
// (64 rows x 32 k = 4KB, double-buffered per wave), staged by the wave itself
// via global_load_lds and ordered by its OWN counted vmcnt(4) — no cross-wave
// sync in the main loop; waves drift freely and fill each other's stalls.
// 32 steps (s 0..3 N-subtiles x ks 0..7 K-slices), 16 MFMA/step.
// LDS = A 64KB + B 8x2x4KB = 64KB + q 16KB = 144KB (1 block/CU, 8 waves).
// Cost: wr-pairs duplicate W reads (2x L2 traffic, well under L2 ceiling).
// Swapped-operand MFMA: D col(lane&15)=pixel, row((lane>>4)*4+j)=W-row.
// W row r (0..1023) = k*32+v: per (s,ni): k = s*8+wn*2+(ni>>1) wave-uniform,
// v = (ni&1)*16+hi*4+j lane-local -> contraction after ks==7 is lane-local
// FMA with scalar q from LDS (f32, chunk-swizzled). Epilogue = champion's.
__global__ __launch_bounds__(512, 2) void fused_qkv_attn(const u16* __restrict__ Xbf,
                                                         const u16* __restrict__ Wbf,
                                                         u16* __restrict__ Abf) {
  __shared__ u16 A_lds[128 * 256];     // 64 KB; f32 partials overlay in epilogue
  __shared__ u16 B_lds[8][2][2048];    // 64 KB: [wave][slot][4KB]; qv tile overlays front
  __shared__ float q_lds[128 * 32];    // 16 KB, q[pix][k] f32, chunk-swizzled

  const int tid = threadIdx.x;
  const int lane = tid & 63;
  const int l15 = lane & 15;
  const int hi = lane >> 4;
  const int wid = tid >> 6;   // 0..7
  const int wr = wid >> 2;    // pixel half
  const int wn = wid & 3;     // 64-row band of each 256-row N-subtile
  const int wm = wr * 64;

  const int head = blockIdx.x & 7;   // head pinned per XCD (heuristic)
  const int pixtile = blockIdx.x >> 3;
  const u16* Ag = Xbf + (size_t)pixtile * 128 * CDIM;
  const u16* Wh = Wbf + (size_t)head * QKVD * CDIM;
  u16* ring = &B_lds[0][0][0];

  // ---- prologue: A tile + qv tile (global pre-swizzled, LDS linear) ----
#pragma unroll
  for (int i = 0; i < 8; ++i) {
    const int seg = wid * 8 + i;
    const int L = seg * 64 + lane;         // 16B chunk 0..4095
    const int row = L >> 5;                // 0..127
    const int c = L & 31;
    const int cs = (c & 24) | ((c & 7) ^ (row & 7));
    gload_lds16(Ag + (size_t)row * CDIM + cs * 8, (char*)A_lds + (size_t)seg * 1024);
  }
#pragma unroll
  for (int i = 0; i < 4; ++i) {
    const int seg = wid * 4 + i;
    const int L = seg * 64 + lane;         // 0..2047
    const int row = L >> 5;                // 0..63
    const int c = L & 31;
    const int cs = (c & 24) | ((c & 7) ^ (row & 7));
    const int grow = row < 32 ? row : row + 1024;  // q rows 0..31, v rows 1056..1087
    gload_lds16(Wh + (size_t)grow * CDIM + cs * 8, (char*)ring + (size_t)seg * 1024);
  }
  WAITVM(0);
  __syncthreads();

  auto afrag = [&](int mi, int kb, int kk2) -> bf16x8 {
    const int row = wm + mi * 16 + l15;
    const int ch = kb * 8 + ((kk2 * 4 + hi) ^ (row & 7));
    return *(const bf16x8*)(A_lds + row * 256 + ch * 8);
  };

  // ---- qv sub-GEMM: wave (wr,wn): 64 pix x 16 qv-cols ----
  f32x4 accq[4] = {};
  {
    const int brow = wn * 16 + l15;
#pragma unroll
    for (int kb = 0; kb < 4; ++kb)
#pragma unroll
      for (int kk2 = 0; kk2 < 2; ++kk2) {
        const int bch = kb * 8 + ((kk2 * 4 + hi) ^ (brow & 7));
        const bf16x8 bq = *(const bf16x8*)(ring + brow * 256 + bch * 8);
#pragma unroll
        for (int mi = 0; mi < 4; ++mi)
          accq[mi] = __builtin_amdgcn_mfma_f32_16x16x32_bf16(bq, afrag(mi, kb, kk2),
                                                             accq[mi], 0, 0, 0);
      }
  }
  if (wn < 2) {  // stash q[pix][k] f32, chunk-swizzled (k = wn*16+hi*4+j)
#pragma unroll
    for (int mi = 0; mi < 4; ++mi) {
      const int pix = wm + mi * 16 + l15;
      *(f32x4*)(q_lds + pix * 32 + ((wn * 4 + hi) ^ (pix & 7)) * 4) = accq[mi];
    }
  }
  __syncthreads();  // q visible; qv reads done -> B region free for slabs

  // ---- main loop: 32 wave-private steps, NO barriers ----
  f32x4 acc[4][4] = {};
  f32x4 qkr[4][2] = {};

  auto stage = [&](int t) {  // stage slab t into own slot t&1 (4 gloads)
    const int s = t >> 3, ks = t & 7;
    char* dst = (char*)&B_lds[wid][t & 1][0];
    const u16* src = Wh + (size_t)(32 + s * 256 + wn * 64) * CDIM + ks * 32;
#pragma unroll
    for (int i = 0; i < 4; ++i) {
      const int row = i * 16 + (lane >> 2);      // linear: i*1024 + lane*16 bytes
      const int cs = (lane & 3) ^ (row & 3);     // pre-swizzled source chunk
      gload_lds16(src + (size_t)row * CDIM + cs * 8, dst + i * 1024);
    }
  };

  auto mstep = [&](int t) {
    const int ks = t & 7;
    const u16* bs = &B_lds[wid][t & 1][0];
    bf16x8 bfr[4], af[4];
#pragma unroll
    for (int ni = 0; ni < 4; ++ni) {
      const int row = ni * 16 + l15;
      bfr[ni] = *(const bf16x8*)(bs + row * 32 + (hi ^ (row & 3)) * 8);
    }
#pragma unroll
    for (int mi = 0; mi < 4; ++mi) af[mi] = afrag(mi, ks >> 1, ks & 1);
    __builtin_amdgcn_s_setprio(1);
#pragma unroll
    for (int mi = 0; mi < 4; ++mi)
#pragma unroll
      for (int ni = 0; ni < 4; ++ni)
        acc[mi][ni] = __builtin_amdgcn_mfma_f32_16x16x32_bf16(bfr[ni], af[mi],
                                                              acc[mi][ni], 0, 0, 0);
    __builtin_amdgcn_s_setprio(0);
    if (ks == 7) {  // contraction for subtile s: k = s*8+wn*2+kp wave-uniform
      const int s = t >> 3;
#pragma unroll
      for (int mi = 0; mi < 4; ++mi) {
        const int pix = wm + mi * 16 + l15;
        const float* qrow = q_lds + pix * 32;
#pragma unroll
        for (int kp = 0; kp < 2; ++kp) {
          const int k = s * 8 + wn * 2 + kp;
          const float qv_ = qrow[((k >> 2) ^ (pix & 7)) * 4 + (k & 3)];
          qkr[mi][0] += qv_ * acc[mi][kp * 2 + 0];
          qkr[mi][1] += qv_ * acc[mi][kp * 2 + 1];
        }
#pragma unroll
        for (int ni = 0; ni < 4; ++ni) acc[mi][ni] = (f32x4){0.f, 0.f, 0.f, 0.f};
      }
    }
  };

  stage(0);
  stage(1);                      // 8 outstanding (own)
#pragma unroll 1
  for (int t = 0; t < 32; ++t) {
    if (t == 31) { WAITVM(0); } else { WAITVM(4); }  // slab t landed, t+1 in flight
    mstep(t);
    __builtin_amdgcn_sched_barrier(0);  // frag reads of slot t&1 stay above overwrite
    if (t < 30) stage(t + 2);           // refill own slot t&1
  }

  // ---- epilogue: cross-wave k-reduction + softmax + a = p*v ----
  __syncthreads();                 // all waves done with A_lds / q_lds
  float* part = (float*)A_lds;     // [wn 4][pix 128][v 32] f32 = 64 KB
#pragma unroll
  for (int mi = 0; mi < 4; ++mi)
#pragma unroll
    for (int par = 0; par < 2; ++par) {
      const int pix = wm + mi * 16 + l15;
      const int ch = (par * 4 + hi) ^ (pix & 7);
      *(f32x4*)(part + wn * 4096 + pix * 32 + ch * 4) = qkr[mi][par];
    }
  __syncthreads();

  const float scale = 0.17677669529663687f;  // 1/sqrt(32)
#pragma unroll
  for (int mi = 0; mi < 4; ++mi) {
    const int pix = wm + mi * 16 + l15;
    const int ch0 = hi ^ (pix & 7);
    const int ch1 = (4 + hi) ^ (pix & 7);
    f32x4 q0 = {0.f, 0.f, 0.f, 0.f}, q1 = {0.f, 0.f, 0.f, 0.f};
#pragma unroll
    for (int w = 0; w < 4; ++w) {
      q0 += *(const f32x4*)(part + w * 4096 + pix * 32 + ch0 * 4);
      q1 += *(const f32x4*)(part + w * 4096 + pix * 32 + ch1 * 4);
    }
    q0 *= scale; q1 *= scale;
    float m = fmaxf(fmaxf(fmaxf(q0.x, q0.y), fmaxf(q0.z, q0.w)),
                    fmaxf(fmaxf(q1.x, q1.y), fmaxf(q1.z, q1.w)));
    m = fmaxf(m, __shfl_xor(m, 16));
    m = fmaxf(m, __shfl_xor(m, 32));
    f32x4 e0, e1;
    e0.x = __expf(q0.x - m); e0.y = __expf(q0.y - m);
    e0.z = __expf(q0.z - m); e0.w = __expf(q0.w - m);
    e1.x = __expf(q1.x - m); e1.y = __expf(q1.y - m);
    e1.z = __expf(q1.z - m); e1.w = __expf(q1.w - m);
    float su = e0.x + e0.y + e0.z + e0.w + e1.x + e1.y + e1.z + e1.w;
    su += __shfl_xor(su, 16);
    su += __shfl_xor(su, 32);
    if (wn >= 2) {  // waves wn>=2 hold v (accq) for v-half wn-2; a = p*v
      const float inv = 1.0f / su;
      const f32x4 a = (wn == 2 ? e0 : e1) * (accq[mi] * inv);
      u32x2 p;
      p.x = (unsigned)f2bf(a.x) | ((unsigned)f2bf(a.y) << 16);
      p.y = (unsigned)f2bf(a.z) | ((unsigned)f2bf(a.w) << 16);
      const size_t gp = (size_t)(pixtile * 128 + pix) * 256 + head * 32 + (wn - 2) * 16 + hi * 4;
      *(u32x2*)(Abf + gp) = p;
    }
  }
}

// ---------------------------------------------------------------------------
// gemm2: out = a @ Wc^T + bc -> (B, C, 4096). 128x128, 2-phase dbuf, swizzled.
__global__ __launch_bounds__(256, 2) void gemm_out(const u16* __restrict__ A,
                                                   const u16* __restrict__ B,
                                                   float* __restrict__ Cout,
                                                   const float* __restrict__ bias) {
  __shared__ u16 As[2][128 * 64];
  __shared__ u16 Bs[2][128 * 64];
  const int tid = threadIdx.x;
  const int lane = tid & 63;
  const int wv = tid >> 6;
  const size_t m0 = (size_t)blockIdx.y * 128;
  const size_t n0 = (size_t)blockIdx.x * 128;
  const int wm = (wv >> 1) * 64;
  const int wn = (wv & 1) * 64;
  const int frow = lane & 15;
  const int fh = lane >> 4;
  const int fsw = frow & 7;

  f32x4 acc[4][4] = {};

  auto stage = [&](int buf, int kt) {
#pragma unroll
    for (int i = 0; i < 4; ++i) {
      const int L = (i * 4 + wv) * 64 + lane;
      const int r = L >> 3;
      const int cs = (L & 7) ^ (r & 7);
      const size_t goff = (size_t)r * CDIM + kt * 64 + cs * 8;
      gload_lds16(A + m0 * CDIM + goff, (char*)As[buf] + (size_t)(i * 4 + wv) * 1024);
      gload_lds16(B + n0 * CDIM + goff, (char*)Bs[buf] + (size_t)(i * 4 + wv) * 1024);
    }
  };

  stage(0, 0);
#pragma unroll
  for (int kt = 0; kt < 4; ++kt) {
    __syncthreads();
    if (kt < 3) stage((kt + 1) & 1, kt + 1);
    const u16* as = As[kt & 1];
    const u16* bs = Bs[kt & 1];
#pragma unroll
    for (int kk2 = 0; kk2 < 2; ++kk2) {
      const int kc = (kk2 * 4 + fh) ^ fsw;
      bf16x8 af[4], bfr[4];
#pragma unroll
      for (int mi = 0; mi < 4; ++mi)
        af[mi] = *(const bf16x8*)(as + (wm + mi * 16 + frow) * 64 + kc * 8);
#pragma unroll
      for (int ni = 0; ni < 4; ++ni)
        bfr[ni] = *(const bf16x8*)(bs + (wn + ni * 16 + frow) * 64 + kc * 8);
#pragma unroll
      for (int mi = 0; mi < 4; ++mi)
#pragma unroll
        for (int ni = 0; ni < 4; ++ni)
          acc[mi][ni] =
              __builtin_amdgcn_mfma_f32_16x16x32_bf16(af[mi], bfr[ni], acc[mi][ni], 0, 0, 0);
    }
  }

#pragma unroll
  for (int mi = 0; mi < 4; ++mi)
#pragma unroll
    for (int ni = 0; ni < 4; ++ni) {
      const size_t gm = m0 + wm + mi * 16 + fh * 4;
      const size_t gn = n0 + wn + ni * 16 + frow;
      f32x4 v = acc[mi][ni];
      v += bias[gn];
      const size_t b = gm >> 12;
      const size_t pix = gm & 4095;
      *(f32x4*)(Cout + ((b << 8) + gn) * 4096 + pix) = v;
    }
}

// ---------------------------------------------------------------------------
extern "C" void kernel_launch(void* const* d_in, const int* in_sizes, int n_in,
                              void* d_out, int out_size, void* d_ws, size_t ws_size,
                              hipStream_t stream) {
  (void)in_sizes; (void)n_in; (void)out_size; (void)ws_size;
  const float* x = (const float*)d_in[0];     // (4, 256, 64, 64)
  const float* Wqkv = (const float*)d_in[1];  // (8, 1088, 256)
  const float* Wc = (const float*)d_in[2];    // (256, 256)
  const float* bc = (const float*)d_in[3];    // (256,)
  float* out = (float*)d_out;                 // (4, 256, 64, 64)
  char* ws = (char*)d_ws;

  const size_t XBF_OFF = 0;               // 16384*256*2 = 8388608
  const size_t WBF_OFF = 8388608;         // 8704*256*2  = 4456448
  const size_t WCBF_OFF = 12845056;       // 256*256*2   = 131072
  const size_t ABF_OFF = 12976128;        // 16384*256*2 = 8388608
  u16* Xbf = (u16*)(ws + XBF_OFF);
  u16* Wbf = (u16*)(ws + WBF_OFF);
  u16* Wcbf = (u16*)(ws + WCBF_OFF);
  u16* Abf = (u16*)(ws + ABF_OFF);

  // stage 0: convert inputs to bf16
  transpose_cast<<<dim3(64, 4, 4), 256, 0, stream>>>(x, Xbf);
  cast_bf<<<(NQKV * CDIM) / 1024, 256, 0, stream>>>(Wqkv, Wbf, NQKV * CDIM);
  cast_bf<<<(CDIM * 256) / 1024, 256, 0, stream>>>(Wc, Wcbf, CDIM * 256);

  // stage 1: fused qkv-GEMM + attention (128 pix x 1 head per block,
  // wave-private B slabs, barrier-free main loop, 144 KB LDS)
  fused_qkv_attn<<<dim3((NPIX_TOTAL / 128) * NHEADS), 512, 0, stream>>>(Xbf, Wbf, Abf);

  // stage 2: out = a @ Wc^T + bc -> (B, C, 4096)
  gemm_out<<<dim3(256 / 128, NPIX_TOTAL / 128), 256, 0, stream>>>(Abf, Wcbf, out, bc);
}